// Round 10
// baseline (312.393 us; speedup 1.0000x reference)
//
#include <hip/hip_runtime.h>
#include <math.h>

// Problem constants:
//   WH=WW=16, N=256 tokens/window, H=6 heads, DIM=192, hd=32
//   B_=256 windows, nW=64 mask windows, qk_scale = 32^-0.5
#define N_TOK 256
#define NHEADS 6
#define DIM_C 192
#define HD 32
#define B_WIN 256

typedef short bf16x8 __attribute__((ext_vector_type(8)));   // 8 bf16 in 4 VGPRs
typedef float f32x4 __attribute__((ext_vector_type(4)));

__device__ inline short f2bf(float f) {          // RNE
    unsigned u = __float_as_uint(f);
    u = (u + 0x7fffu + ((u >> 16) & 1u)) >> 16;
    return (short)u;
}
__device__ inline short f2bf_fast(float f) {     // round-half-up (0.5 ulp)
    return (short)((__float_as_uint(f) + 0x8000u) >> 16);
}
__device__ inline float bf2f(short s) {
    return __uint_as_float(((unsigned)(unsigned short)s) << 16);
}
// packed RNE f32x2 -> bf16x2 (one VALU op)
__device__ inline unsigned cvt_pk_bf16(float lo, float hi) {
    unsigned r;
    asm("v_cvt_pk_bf16_f32 %0, %1, %2" : "=v"(r) : "v"(lo), "v"(hi));
    return r;
}

// ---------------------------------------------------------------------------
// Kernel 1: CPB MLP -> table (961 x 6) fp32
// ---------------------------------------------------------------------------
__global__ __launch_bounds__(512) void cpb_table_kernel(
    const float* __restrict__ scale, const float* __restrict__ w1,
    const float* __restrict__ b1, const float* __restrict__ w2,
    const float* __restrict__ b2, float* __restrict__ table)
{
    __shared__ float red[512];
    const int e = blockIdx.x;            // 0..960
    const int i = e / 31, j = e % 31;
    const float t0 = ((float)(i - 15)) * (8.0f / 15.0f);
    const float t1 = ((float)(j - 15)) * (8.0f / 15.0f);
    const float s0 = scale[0], s1 = scale[1];
    const int t = threadIdx.x;
    const float* w = w1 + t * 4;
    float h = w[0] * t0 + w[1] * t1 + w[2] * s0 + w[3] * s1 + b1[t];
    h = fmaxf(h, 0.0f);
    for (int head = 0; head < NHEADS; ++head) {
        red[t] = h * w2[head * 512 + t];
        __syncthreads();
        for (int s = 256; s > 0; s >>= 1) {
            if (t < s) red[t] += red[t + s];
            __syncthreads();
        }
        if (t == 0) table[e * NHEADS + head] = red[0] + b2[head];
        __syncthreads();
    }
}

// ---------------------------------------------------------------------------
// TRANSPOSED perm layout (for swapped QK^T: S^T = mfma(K, Q, C)).
// Slab (65536 bf16): offset = ((rb*8 + g)*64 + lane)*8 + (nt&1)*4 + r
//   value = src[q = rb*16 + (lane&15)][k = nt*16 + (lane>>4)*4 + r]
// ---------------------------------------------------------------------------

// Kernel 2a: bias -> transposed-perm bf16 (6 slabs).
__global__ __launch_bounds__(256) void bias_perm_kernel(
    const float* __restrict__ table, short* __restrict__ bias_p)
{
    const int idx8 = blockIdx.x * 256 + threadIdx.x;   // < 6*8192
    const int h = idx8 >> 13;
    const int rem = idx8 & 8191;
    const int rb = rem >> 9;
    const int g = (rem >> 6) & 7;
    const int lane = rem & 63;
    const int quad = lane >> 4, l15 = lane & 15;
    bf16x8 o;
#pragma unroll
    for (int j = 0; j < 8; ++j) {
        const int nt = g * 2 + (j >> 2), r = j & 3;
        const int rel0 = rb - nt + 15;                       // (q>>4)-(k>>4)+15
        const int rel1 = l15 - (quad * 4 + r) + 15;          // (q&15)-(k&15)+15
        o[j] = f2bf(table[(rel0 * 31 + rel1) * NHEADS + h]);
    }
    ((bf16x8*)bias_p)[idx8] = o;
}

// Kernel 2b: mask -> transposed-perm bf16 (64 slabs).
__global__ __launch_bounds__(256) void mask_perm_kernel(
    const float* __restrict__ mask, short* __restrict__ mask_p)
{
    const int idx8 = blockIdx.x * 256 + threadIdx.x;   // < 64*8192
    const int bw = idx8 >> 13;
    const int rem = idx8 & 8191;
    const int rb = rem >> 9;
    const int g = (rem >> 6) & 7;
    const int lane = rem & 63;
    const int quad = lane >> 4, l15 = lane & 15;
    const float* ms = mask + ((size_t)bw << 16);
    bf16x8 o;
#pragma unroll
    for (int j = 0; j < 8; ++j) {
        const int nt = g * 2 + (j >> 2), r = j & 3;
        const int q = rb * 16 + l15;
        const int k = nt * 16 + quad * 4 + r;
        o[j] = f2bf(ms[q * 256 + k]);
    }
    ((bf16x8*)mask_p)[idx8] = o;
}

// ---------------------------------------------------------------------------
// Kernel 2c: generic fp32 -> bf16 (n4 = count/4)
// ---------------------------------------------------------------------------
__global__ __launch_bounds__(256) void f32_to_bf16_kernel(
    const float* __restrict__ in, short* __restrict__ out, int n4)
{
    const int i = blockIdx.x * 256 + threadIdx.x;
    if (i < n4) {
        float4 v = ((const float4*)in)[i];
        short4 s;
        s.x = f2bf(v.x); s.y = f2bf(v.y); s.z = f2bf(v.z); s.w = f2bf(v.w);
        ((short4*)out)[i] = s;
    }
}

// ---------------------------------------------------------------------------
// Kernel 3: QKV GEMM, no LDS, deep-ILP. R9 change: 128-thread (2-wave)
// blocks — same per-wave work (32 rows x 96 cols, af-preload + wb dbuf),
// but 2x finer block granularity so more independent blocks co-reside per
// CU (R7 measured 29% occupancy with 24-wave capacity: residency was
// block-granularity-limited, not resource-limited).
// Grid 6144 = 8 xcd * 128 panel-groups(64 rows) * 6 col-blocks.
// ---------------------------------------------------------------------------
__global__ __launch_bounds__(128) void qkv_gemm_kernel(
    const short* __restrict__ x16, const short* __restrict__ w16,
    const float* __restrict__ qkv_b,
    short* __restrict__ qb, short* __restrict__ kb, short* __restrict__ vb)
{
    const int t = threadIdx.x;
    const int lane = t & 63;
    const int w = t >> 6;                // 0..1
    const int l15 = lane & 15, quad = lane >> 4;

    const int l = blockIdx.x;            // 0..6143
    const int xcd = l & 7;
    const int s = l >> 3;                // 0..767
    const int cb = s % 6;                // col-block 0..5 (96 cols each)
    const int panel = xcd + 8 * (s / 6); // 0..1023 (64-row panels)
    const int m0 = panel * 64 + w * 32;
    const int n0 = cb * 96;

    // preload ALL A fragments: af[mt][ks] (12 x b128), independent
    bf16x8 af[2][6];
#pragma unroll
    for (int mt = 0; mt < 2; ++mt)
#pragma unroll
        for (int ks = 0; ks < 6; ++ks)
            af[mt][ks] = *(const bf16x8*)(x16 + (size_t)(m0 + mt * 16 + l15) * DIM_C + ks * 32 + quad * 8);

    // W double buffer: prime ks=0
    bf16x8 wb[2][6];
#pragma unroll
    for (int c4 = 0; c4 < 6; ++c4)
        wb[0][c4] = *(const bf16x8*)(w16 + (size_t)(n0 + c4 * 16 + l15) * DIM_C + quad * 8);

    f32x4 acc[2][6] = {};
#pragma unroll
    for (int ks = 0; ks < 6; ++ks) {
        if (ks < 5) {
#pragma unroll
            for (int c4 = 0; c4 < 6; ++c4)
                wb[(ks + 1) & 1][c4] = *(const bf16x8*)(w16 + (size_t)(n0 + c4 * 16 + l15) * DIM_C + (ks + 1) * 32 + quad * 8);
        }
#pragma unroll
        for (int mt = 0; mt < 2; ++mt)
#pragma unroll
            for (int c4 = 0; c4 < 6; ++c4)
                acc[mt][c4] = __builtin_amdgcn_mfma_f32_16x16x32_bf16(af[mt][ks], wb[ks & 1][c4], acc[mt][c4], 0, 0, 0);
    }

    const int which = cb >> 1;           // 0=q,1=k,2=v (constant per block)
    short* outp = (which == 0) ? qb : (which == 1) ? kb : vb;
    const float qscale = (which == 0) ? 0.17677669529663689f : 1.0f;
#pragma unroll
    for (int mt = 0; mt < 2; ++mt) {
#pragma unroll
        for (int r = 0; r < 4; ++r) {
            const int m = m0 + mt * 16 + quad * 4 + r;
            const int b = m >> 8, tok = m & 255;
#pragma unroll
            for (int c4 = 0; c4 < 6; ++c4) {
                const int rem = (cb & 1) * 96 + c4 * 16 + l15;   // 0..191
                const int h = rem >> 5, d = rem & 31;
                const float val = (acc[mt][c4][r] + qkv_b[which * DIM_C + rem]) * qscale;
                outp[((size_t)((b * NHEADS + h) * N_TOK + tok)) * HD + d] = f2bf(val);
            }
        }
    }
}

// ---------------------------------------------------------------------------
// Kernel 5: proj GEMM, no LDS, deep-ILP, 128-thread (2-wave) blocks.
//   grid 2048 = 8 xcd * 128 panel-groups(64 rows) * 2 col-blocks
// ---------------------------------------------------------------------------
__global__ __launch_bounds__(128) void proj_gemm_kernel(
    const short* __restrict__ A16, const short* __restrict__ w16,
    const float* __restrict__ proj_b, float* __restrict__ out)
{
    const int t = threadIdx.x;
    const int lane = t & 63;
    const int w = t >> 6;                // 0..1
    const int l15 = lane & 15, quad = lane >> 4;

    const int l = blockIdx.x;            // 0..2047
    const int xcd = l & 7;
    const int s = l >> 3;                // 0..255
    const int cb = s % 2;                // col-block 0..1 (96 cols each)
    const int panel = xcd + 8 * (s / 2); // 0..1023 (64-row panels)
    const int m0 = panel * 64 + w * 32;
    const int n0 = cb * 96;

    bf16x8 af[2][6];
#pragma unroll
    for (int mt = 0; mt < 2; ++mt)
#pragma unroll
        for (int ks = 0; ks < 6; ++ks)
            af[mt][ks] = *(const bf16x8*)(A16 + (size_t)(m0 + mt * 16 + l15) * DIM_C + ks * 32 + quad * 8);

    bf16x8 wb[2][6];
#pragma unroll
    for (int c4 = 0; c4 < 6; ++c4)
        wb[0][c4] = *(const bf16x8*)(w16 + (size_t)(n0 + c4 * 16 + l15) * DIM_C + quad * 8);

    f32x4 acc[2][6] = {};
#pragma unroll
    for (int ks = 0; ks < 6; ++ks) {
        if (ks < 5) {
#pragma unroll
            for (int c4 = 0; c4 < 6; ++c4)
                wb[(ks + 1) & 1][c4] = *(const bf16x8*)(w16 + (size_t)(n0 + c4 * 16 + l15) * DIM_C + (ks + 1) * 32 + quad * 8);
        }
#pragma unroll
        for (int mt = 0; mt < 2; ++mt)
#pragma unroll
            for (int c4 = 0; c4 < 6; ++c4)
                acc[mt][c4] = __builtin_amdgcn_mfma_f32_16x16x32_bf16(af[mt][ks], wb[ks & 1][c4], acc[mt][c4], 0, 0, 0);
    }

#pragma unroll
    for (int mt = 0; mt < 2; ++mt) {
#pragma unroll
        for (int r = 0; r < 4; ++r) {
            const int m = m0 + mt * 16 + quad * 4 + r;
#pragma unroll
            for (int c4 = 0; c4 < 6; ++c4) {
                const int c = n0 + c4 * 16 + l15;
                out[(size_t)m * DIM_C + c] = acc[mt][c4][r] + proj_b[c];
            }
        }
    }
}

// ---------------------------------------------------------------------------
// Kernel 4: MFMA attention, SWAPPED QK^T (R7 exactly — proven at 312 us).
// ---------------------------------------------------------------------------
#define PS_LD 264   // shorts; 528 B/row (16B aligned)

__global__ __launch_bounds__(256, 3) void attn_mfma_kernel(
    const short* __restrict__ q, const short* __restrict__ k,
    const short* __restrict__ v, const short* __restrict__ bias_p,
    const short* __restrict__ mask_p, short* __restrict__ out16)
{
    __shared__ __align__(16) short Vt[32][PS_LD];      // V^T, 16.9 KB
    __shared__ __align__(16) short Pw[4][16][PS_LD];   // per-wave P, 33.8 KB

    // XCD-aware swizzle (bijective on 1536 = 8 xcd * 8 bw-groups * 24 jobs)
    const int l = blockIdx.x;            // 0..1535
    const int s = l >> 3;                // 0..191
    const int bw = (l & 7) + 8 * (s / 24);
    const int j = s % 24;
    const int h = j % 6;                 // 0..5
    const int b = (j / 6) * 64 + bw;     // 0..255

    const int t = threadIdx.x;
    const int lane = t & 63;
    const int w = t >> 6;
    const int l15 = lane & 15;
    const int quad = lane >> 4;
    const size_t slab = ((size_t)(b * NHEADS + h)) * (N_TOK * HD);

    // stage V^T (thread t -> token t), swizzled columns
    {
        const bf16x8* vrow = (const bf16x8*)(v + slab + (size_t)t * HD);
#pragma unroll
        for (int u = 0; u < 4; ++u) {
            bf16x8 vv = vrow[u];
#pragma unroll
            for (int jj = 0; jj < 8; ++jj) {
                const int d = u * 8 + jj;
                Vt[d][t ^ (((d >> 3) & 1) * 16)] = vv[jj];
            }
        }
    }

    // K fragments: chunk-invariant, load once (16 x bf16x8 = 64 VGPRs)
    bf16x8 kfr[16];
#pragma unroll
    for (int nt = 0; nt < 16; ++nt)
        kfr[nt] = *(const bf16x8*)(k + slab + (size_t)(nt * 16 + l15) * HD + quad * 8);

    __syncthreads();   // Vt ready (only barrier in the kernel body)

    const short* bslab = bias_p + h * 65536;
    const short* mslab = mask_p + bw * 65536;
    const int sw = ((l15 >> 3) & 1) * 16;

    for (int chunk = 0; chunk < 4; ++chunk) {
        const int rb = chunk * 4 + w;    // row block 0..15

        // Q fragment: rows rb*16 + l15, d = quad*8..+7 (B-operand: col = q)
        const bf16x8 qf = *(const bf16x8*)(q + slab + (size_t)(rb * 16 + l15) * HD + quad * 8);

        // Swapped QK^T with transposed bias+mask injected as C:
        // S[nt][r] = S[q = rb*16+l15][k = nt*16+quad*4+r]
        f32x4 S[16];
#pragma unroll
        for (int half = 0; half < 2; ++half) {
            bf16x8 bb[4], mm[4];
#pragma unroll
            for (int gg = 0; gg < 4; ++gg) {
                const int g = half * 4 + gg;
                const int off = ((rb * 8 + g) * 64 + lane) * 8;
                bb[gg] = *(const bf16x8*)(bslab + off);
                mm[gg] = *(const bf16x8*)(mslab + off);
            }
#pragma unroll
            for (int gg = 0; gg < 4; ++gg) {
                const int g = half * 4 + gg;
                f32x4 c0, c1;
#pragma unroll
                for (int r = 0; r < 4; ++r) {
                    c0[r] = bf2f(bb[gg][r])     + bf2f(mm[gg][r]);
                    c1[r] = bf2f(bb[gg][4 + r]) + bf2f(mm[gg][4 + r]);
                }
                S[g * 2]     = __builtin_amdgcn_mfma_f32_16x16x32_bf16(kfr[g * 2],     qf, c0, 0, 0, 0);
                S[g * 2 + 1] = __builtin_amdgcn_mfma_f32_16x16x32_bf16(kfr[g * 2 + 1], qf, c1, 0, 0, 0);
            }
        }

        // row max: per-lane + 2 shuffles (lane owns full q-row)
        float mxp[4] = {-1e30f, -1e30f, -1e30f, -1e30f};
#pragma unroll
        for (int nt = 0; nt < 16; ++nt)
#pragma unroll
            for (int r = 0; r < 4; ++r)
                mxp[r] = fmaxf(mxp[r], S[nt][r]);
        float mx = fmaxf(fmaxf(mxp[0], mxp[1]), fmaxf(mxp[2], mxp[3]));
        mx = fmaxf(mx, __shfl_xor(mx, 16));
        mx = fmaxf(mx, __shfl_xor(mx, 32));

        // exp + sum + packed P -> per-wave LDS (b64 writes, swizzled)
        float sm[4] = {0.f, 0.f, 0.f, 0.f};
        short* prow = &Pw[w][l15][0];
#pragma unroll
        for (int nt = 0; nt < 16; ++nt) {
            const float p0 = __expf(S[nt][0] - mx);
            const float p1 = __expf(S[nt][1] - mx);
            const float p2 = __expf(S[nt][2] - mx);
            const float p3 = __expf(S[nt][3] - mx);
            sm[0] += p0; sm[1] += p1; sm[2] += p2; sm[3] += p3;
            uint2 pk;
            pk.x = cvt_pk_bf16(p0, p1);
            pk.y = cvt_pk_bf16(p2, p3);
            *(uint2*)&prow[(nt * 16 + quad * 4) ^ sw] = pk;
        }
        float smt = (sm[0] + sm[1]) + (sm[2] + sm[3]);
        smt += __shfl_xor(smt, 16);
        smt += __shfl_xor(smt, 32);
        const float inv = __builtin_amdgcn_rcpf(smt);

        // wave-local LDS: drain writes before fragment reads
        __asm__ volatile("s_waitcnt lgkmcnt(0)" ::: "memory");

        // PV: O (16 rows x 32 d), A-frags from own Pw, B-frags from Vt
        f32x4 O0 = {0.f, 0.f, 0.f, 0.f};
        f32x4 O1 = {0.f, 0.f, 0.f, 0.f};
#pragma unroll
        for (int ks = 0; ks < 8; ++ks) {
            const int cb = ks * 32 + quad * 8;
            bf16x8 af  = *(const bf16x8*)&Pw[w][l15][cb ^ sw];
            bf16x8 bf0 = *(const bf16x8*)&Vt[l15][cb ^ sw];
            bf16x8 bf1 = *(const bf16x8*)&Vt[16 + l15][cb ^ sw];
            O0 = __builtin_amdgcn_mfma_f32_16x16x32_bf16(af, bf0, O0, 0, 0, 0);
            O1 = __builtin_amdgcn_mfma_f32_16x16x32_bf16(af, bf1, O1, 0, 0, 0);
        }

        // epilogue: output rows quad*4+r; softmax inv lives at lane l15=q
        float inv_e[4];
#pragma unroll
        for (int r = 0; r < 4; ++r)
            inv_e[r] = __shfl(inv, quad * 4 + r);
#pragma unroll
        for (int r = 0; r < 4; ++r) {
            const int token = rb * 16 + quad * 4 + r;
            short* dst = out16 + ((size_t)(b * N_TOK + token)) * DIM_C + h * HD;
            dst[l15]      = f2bf_fast(O0[r] * inv_e[r]);
            dst[16 + l15] = f2bf_fast(O1[r] * inv_e[r]);
        }
    }
}

// ---------------------------------------------------------------------------
// Launch
// ---------------------------------------------------------------------------
extern "C" void kernel_launch(void* const* d_in, const int* in_sizes, int n_in,
                              void* d_out, int out_size, void* d_ws, size_t ws_size,
                              hipStream_t stream)
{
    const float* x      = (const float*)d_in[0];   // (256,256,192)
    const float* scale  = (const float*)d_in[1];   // (1,2)
    const float* mask   = (const float*)d_in[2];   // (64,256,256)
    const float* qkv_w  = (const float*)d_in[3];   // (576,192)
    const float* qkv_b  = (const float*)d_in[4];   // (576,)
    const float* cpb_w1 = (const float*)d_in[5];   // (512,4)
    const float* cpb_b1 = (const float*)d_in[6];   // (512,)
    const float* cpb_w2 = (const float*)d_in[7];   // (6,512)
    const float* cpb_b2 = (const float*)d_in[8];   // (6,)
    const float* proj_w = (const float*)d_in[9];   // (192,192)
    const float* proj_b = (const float*)d_in[10];  // (192,)
    float* out = (float*)d_out;                    // (256,256,192) fp32

    const size_t per = (size_t)B_WIN * NHEADS * N_TOK * HD;  // 12,582,912
    short* wss     = (short*)d_ws;
    short* qb      = wss;
    short* kb      = qb + per;
    short* vb      = kb + per;
    short* ao      = vb + per;
    short* x16     = ao + per;                    // 12,582,912
    short* bias_p  = x16 + per;                   // 6*65536  =   393,216
    short* mask_p  = bias_p + 393216;             // 64*65536 = 4,194,304
    short* qkvw16  = mask_p + 4194304;            // 110,592
    short* projw16 = qkvw16 + 110592;             // 36,864
    float* table   = (float*)(projw16 + 36864);   // 961*6 fp32

    cpb_table_kernel<<<961, 512, 0, stream>>>(scale, cpb_w1, cpb_b1, cpb_w2, cpb_b2, table);

    bias_perm_kernel<<<(NHEADS * 8192) / 256, 256, 0, stream>>>(table, bias_p);
    mask_perm_kernel<<<(64 * 8192) / 256, 256, 0, stream>>>(mask, mask_p);

    f32_to_bf16_kernel<<<(int)((per / 4 + 255) / 256), 256, 0, stream>>>(x, x16, (int)(per / 4));
    f32_to_bf16_kernel<<<(110592 / 4 + 255) / 256, 256, 0, stream>>>(qkv_w, qkvw16, 110592 / 4);
    f32_to_bf16_kernel<<<(36864 / 4 + 255) / 256, 256, 0, stream>>>(proj_w, projw16, 36864 / 4);

    qkv_gemm_kernel<<<6144, 128, 0, stream>>>(x16, qkvw16, qkv_b, qb, kb, vb);

    attn_mfma_kernel<<<NHEADS * B_WIN, 256, 0, stream>>>(qb, kb, vb, bias_p, mask_p, ao);

    proj_gemm_kernel<<<2048, 128, 0, stream>>>(ao, projw16, proj_b, out);
}